// Round 5
// baseline (975.896 us; speedup 1.0000x reference)
//
#include <hip/hip_runtime.h>
#include <hip/hip_bf16.h>

// ---------------------------------------------------------------------------
// HybridGATLSTM on MI355X — round 5.
//   lstm_batch : 16 blocks (one per batch element), 256 threads.
//                proj = M=96 MFMA GEMM (split-fp16, 4 waves x 2 row-groups)
//                rec  = fp32 VALU GEMV, 2 gate-rows/thread (halves LDS
//                       broadcast traffic), all 4 gates of a hidden unit in
//                       one wave -> shfl_xor(32) exchange, 1 barrier/step.
//   gat_prep   : per-graph GAT math -> stats (Lv,Rv,mx,rd) stored in the
//                first 512 floats of the block's own attn region + xg.
//   gat_write  : streaming masked-softmax writer (float4, 100 MB).
//   head_*     : unchanged.
// LSTM Pre scratch lives in the attn2 region of d_out (gat runs after).
// ---------------------------------------------------------------------------

typedef _Float16 half8 __attribute__((ext_vector_type(8)));
typedef float floatx4 __attribute__((ext_vector_type(4)));
typedef float float4v __attribute__((ext_vector_type(4)));

#define LOG2E 1.44269504088896f

__device__ __forceinline__ float fast_exp(float x) {
    return __builtin_amdgcn_exp2f(x * LOG2E);
}
__device__ __forceinline__ float sigm(float x) {
    x = fminf(fmaxf(x, -30.f), 30.f);
    return __builtin_amdgcn_rcpf(1.f + __builtin_amdgcn_exp2f(-x * LOG2E));
}
__device__ __forceinline__ float tanhp(float x) {
    x = fminf(fmaxf(x, -15.f), 15.f);
    float e = __builtin_amdgcn_exp2f(-2.f * LOG2E * x);
    return (1.f - e) * __builtin_amdgcn_rcpf(1.f + e);
}
__device__ __forceinline__ void split8v(float4v v0, float4v v1, half8& hi, half8& lo) {
#pragma unroll
    for (int j = 0; j < 4; ++j) {
        _Float16 h = (_Float16)v0[j];
        hi[j] = h; lo[j] = (_Float16)(v0[j] - (float)h);
    }
#pragma unroll
    for (int j = 0; j < 4; ++j) {
        _Float16 h = (_Float16)v1[j];
        hi[4 + j] = h; lo[4 + j] = (_Float16)(v1[j] - (float)h);
    }
}

// ---------------------------------------------------------------------------
// One block per batch element. Layers sequential; no cross-block traffic.
// ---------------------------------------------------------------------------
__global__ __launch_bounds__(256, 1) void lstm_batch_kernel(
    const float* __restrict__ x,     // [16][96][128]
    const float* __restrict__ Wih,   // [3][512][128]
    const float* __restrict__ Whh,   // [3][512][128]
    const float* __restrict__ bih,   // [3][512]
    const float* __restrict__ bhh,   // [3][512]
    float* __restrict__ scratch,     // per block: 3 * 96*512 floats (Pre)
    float* __restrict__ xl_out)      // [16][128]
{
    int b = blockIdx.x;
    float* PreBase = scratch + b * (3 * 96 * 512);

    int tid = threadIdx.x;
    int w = tid >> 6, lane = tid & 63, quad = lane >> 4, sub = lane & 15;
    int lane31 = lane & 31, half = lane >> 5;

    __shared__ float hbuf[2][128];     // double-buffered h (fp32)
    __shared__ float Hseq[96 * 132];   // layer output sequence (padded rows)

    for (int layer = 0; layer < 3; ++layer) {
        const float* WihL = Wih + layer * 65536;
        const float* WhhL = Whh + layer * 65536;
        float* Pre = PreBase + layer * (96 * 512);

        // ======== proj GEMM (MFMA, split-fp16): Pre[t][r] = A[t].Wih[r]+bias
        // 4 waves; wave w covers row-groups ww = 2w, 2w+1 (rows tt*128+16ww+sub)
        for (int wi = 0; wi < 2; ++wi) {
            int ww = 2 * w + wi;
            half8 bhi[4][4], blo[4][4];
            float bias[4];
#pragma unroll
            for (int tt = 0; tt < 4; ++tt) {
                int r = tt * 128 + 16 * ww + sub;
                bias[tt] = bih[layer * 512 + r] + bhh[layer * 512 + r];
#pragma unroll
                for (int kc = 0; kc < 4; ++kc) {
                    const float4v* p = (const float4v*)(WihL + r * 128 + kc * 32 + quad * 8);
                    split8v(p[0], p[1], bhi[tt][kc], blo[tt][kc]);
                }
            }
            for (int mt = 0; mt < 6; ++mt) {
                half8 ahi[4], alo[4];
                if (layer == 0) {
                    const float* arow = x + b * 12288 + (mt * 16 + sub) * 128;
#pragma unroll
                    for (int kc = 0; kc < 4; ++kc) {
                        const float4v* p = (const float4v*)(arow + kc * 32 + quad * 8);
                        split8v(p[0], p[1], ahi[kc], alo[kc]);
                    }
                } else {
                    const float* arow = Hseq + (mt * 16 + sub) * 132;
#pragma unroll
                    for (int kc = 0; kc < 4; ++kc) {
                        const float4v* p = (const float4v*)(arow + kc * 32 + quad * 8);
                        split8v(p[0], p[1], ahi[kc], alo[kc]);
                    }
                }
                floatx4 acc[4];
#pragma unroll
                for (int tt = 0; tt < 4; ++tt) {
                    floatx4 a = {bias[tt], bias[tt], bias[tt], bias[tt]};
                    acc[tt] = a;
                }
#pragma unroll
                for (int tt = 0; tt < 4; ++tt)
#pragma unroll
                    for (int kc = 0; kc < 4; ++kc) {
                        acc[tt] = __builtin_amdgcn_mfma_f32_16x16x32_f16(ahi[kc], bhi[tt][kc], acc[tt], 0, 0, 0);
                        acc[tt] = __builtin_amdgcn_mfma_f32_16x16x32_f16(ahi[kc], blo[tt][kc], acc[tt], 0, 0, 0);
                        acc[tt] = __builtin_amdgcn_mfma_f32_16x16x32_f16(alo[kc], bhi[tt][kc], acc[tt], 0, 0, 0);
                    }
                // store: timestep m = mt*16 + quad*4 + reg, row = tt*128+16ww+sub
#pragma unroll
                for (int tt = 0; tt < 4; ++tt)
#pragma unroll
                    for (int reg = 0; reg < 4; ++reg)
                        Pre[(mt * 16 + quad * 4 + reg) * 512 + tt * 128 + 16 * ww + sub] = acc[tt][reg];
            }
        }

        // ======== recurrence: thread owns 2 gate rows of hidden unit hu.
        // lanes 0-31: rows (hu, 128+hu) = (i,f); lanes 32-63: (256+hu, 384+hu)
        // = (g,o). Partner exchange via shfl_xor(32) — no barrier needed.
        int hu = 32 * w + lane31;
        int r0 = half ? (256 + hu) : hu;
        int r1 = half ? (384 + hu) : (128 + hu);
        float4v wA[32], wB[32];
        {
            const float4v* pa = (const float4v*)(WhhL + r0 * 128);
            const float4v* pb = (const float4v*)(WhhL + r1 * 128);
#pragma unroll
            for (int k = 0; k < 32; ++k) { wA[k] = pa[k]; wB[k] = pb[k]; }
        }
        if (tid < 128) hbuf[0][tid] = 0.f;
        float cvar = 0.f;
        __syncthreads();   // Pre stores drained; hbuf zeroed; Hseq reads done

        for (int t = 0; t < 96; ++t) {
            int rb = t & 1, wb = rb ^ 1;
            float preA = Pre[t * 512 + r0];   // global, issued early
            float preB = Pre[t * 512 + r1];
            const float4v* h4 = (const float4v*)hbuf[rb];
            float4v sA = {0.f, 0.f, 0.f, 0.f};
            float4v sB = {0.f, 0.f, 0.f, 0.f};
#pragma unroll
            for (int k = 0; k < 32; ++k) {
                float4v hv = h4[k];
                sA += wA[k] * hv;
                sB += wB[k] * hv;
            }
            float gA = preA + sA.x + sA.y + sA.z + sA.w;
            float gB = preB + sB.x + sB.y + sB.z + sB.w;
            float oA = __shfl_xor(gA, 32, 64);
            float oB = __shfl_xor(gB, 32, 64);
            float gi = half ? oA : gA;
            float gf = half ? oB : gB;
            float gg = half ? gA : oA;
            float go = half ? gB : oB;
            float c = sigm(gf) * cvar + sigm(gi) * tanhp(gg);
            cvar = c;
            float h = sigm(go) * tanhp(c);
            if (!half) {
                hbuf[wb][hu] = h;
                if (layer < 2) Hseq[t * 132 + hu] = h;
                else if (t == 95) xl_out[b * 128 + hu] = h;
            }
            __syncthreads();   // h visible; all reads of rb complete
        }
    }
}

// ---------------------------------------------------------------------------
// GAT prep: per-graph stats. Writes [Lv|Rv|mx2|rd2] (512 floats) into the
// first 512 floats of this block's OWN attn region (gat_write stages them to
// LDS before overwriting). Also computes xg for s==95 graphs.
// ---------------------------------------------------------------------------
__global__ __launch_bounds__(256) void gat_prep_kernel(
    const float* __restrict__ x, const float* __restrict__ adj,
    const float* __restrict__ W_emb, const float* __restrict__ b_emb,
    const float* __restrict__ W1, const float* __restrict__ a1,
    const float* __restrict__ W2, const float* __restrict__ a2,
    float* __restrict__ attn_out, float* __restrict__ xg)
{
    int m = blockIdx.x;
    int tid = threadIdx.x;
    __shared__ float xv[128];
    __shared__ unsigned char adjb[128 * 132];
    __shared__ float u1[32], v1[32];
    __shared__ float coef[4];
    __shared__ float s1v[128];
    __shared__ float h2s[128 * 33];
    __shared__ float wh2[128 * 17];
    __shared__ float Lv[128], Rv[128], mx2[128], rd2[128];
    __shared__ float m_h[2][128], d_h[2][128], s_h[2][128];

    if (tid < 128) xv[tid] = x[m * 128 + tid];
    for (int idx = tid; idx < 16384; idx += 256) {
        int i = idx >> 7, j = idx & 127;
        adjb[i * 132 + j] = adj[idx] > 0.f ? 1 : 0;
    }
    if (tid < 32) {
        float su = 0.f, sv = 0.f;
        for (int kk = 0; kk < 32; ++kk) {
            su += W_emb[kk] * W1[kk * 32 + tid];
            sv += b_emb[kk] * W1[kk * 32 + tid];
        }
        u1[tid] = su; v1[tid] = sv;
    }
    __syncthreads();
    if (tid < 4) {
        const float* av = a1 + ((tid >= 2) ? 32 : 0);
        const float* uv = (tid & 1) ? v1 : u1;
        float s = 0.f;
        for (int f = 0; f < 32; ++f) s += uv[f] * av[f];
        coef[tid] = s;
    }
    __syncthreads();
    float cL = coef[0], dL = coef[1], cR = coef[2], dR = coef[3];

    // GAT1 softmax stats + weighted scalar sum (FI=1 collapse)
    {
        int i = tid & 127, hf = tid >> 7;
        float Li = xv[i] * cL + dL;
        int j0 = hf * 64;
        float mmax = -3.0e38f;
        for (int j = j0; j < j0 + 64; ++j) {
            if (adjb[i * 132 + j]) {
                float e = Li + xv[j] * cR + dR;
                e = e > 0.f ? e : 0.2f * e;
                mmax = fmaxf(mmax, e);
            }
        }
        float den = 0.f, wsum = 0.f;
        for (int j = j0; j < j0 + 64; ++j) {
            if (adjb[i * 132 + j]) {
                float e = Li + xv[j] * cR + dR;
                e = e > 0.f ? e : 0.2f * e;
                float p = fast_exp(e - mmax);
                den += p; wsum += p * xv[j];
            }
        }
        m_h[hf][i] = mmax; d_h[hf][i] = den; s_h[hf][i] = wsum;
    }
    __syncthreads();
    if (tid < 128) {
        int i = tid;
        float m0 = m_h[0][i], m1 = m_h[1][i];
        float mm = fmaxf(m0, m1);
        float sc0 = fast_exp(m0 - mm), sc1 = fast_exp(m1 - mm);
        float den = d_h[0][i] * sc0 + d_h[1][i] * sc1;
        float wsum = s_h[0][i] * sc0 + s_h[1][i] * sc1;
        s1v[i] = wsum / den;
    }
    __syncthreads();
    // h2 = elu(s1*u1 + v1)
    for (int e = tid; e < 4096; e += 256) {
        int i = e >> 5, f = e & 31;
        float v = s1v[i] * u1[f] + v1[f];
        h2s[i * 33 + f] = v > 0.f ? v : fast_exp(v) - 1.f;
    }
    __syncthreads();
    // Wh2 = h2 @ W2 (128x32 @ 32x16)
    {
        int i = tid >> 1, g0 = (tid & 1) * 8;
        float accv[8] = {0.f, 0.f, 0.f, 0.f, 0.f, 0.f, 0.f, 0.f};
        for (int f = 0; f < 32; ++f) {
            float hv = h2s[i * 33 + f];
#pragma unroll
            for (int g = 0; g < 8; ++g) accv[g] += hv * W2[f * 16 + g0 + g];
        }
#pragma unroll
        for (int g = 0; g < 8; ++g) wh2[i * 17 + g0 + g] = accv[g];
    }
    __syncthreads();
    {
        int i = tid & 127, which = tid >> 7;
        const float* aa = a2 + which * 16;
        float s = 0.f;
        for (int g = 0; g < 16; ++g) s += wh2[i * 17 + g] * aa[g];
        (which ? Rv : Lv)[i] = s;
    }
    __syncthreads();
    // attn2 softmax stats
    {
        int i = tid & 127, hf = tid >> 7;
        float Li = Lv[i];
        int j0 = hf * 64;
        float mmax = -3.0e38f;
        for (int j = j0; j < j0 + 64; ++j) {
            if (adjb[i * 132 + j]) {
                float e = Li + Rv[j];
                e = e > 0.f ? e : 0.2f * e;
                mmax = fmaxf(mmax, e);
            }
        }
        float den = 0.f;
        for (int j = j0; j < j0 + 64; ++j) {
            if (adjb[i * 132 + j]) {
                float e = Li + Rv[j];
                e = e > 0.f ? e : 0.2f * e;
                den += fast_exp(e - mmax);
            }
        }
        m_h[hf][i] = mmax; d_h[hf][i] = den;
    }
    __syncthreads();
    if (tid < 128) {
        int i = tid;
        float m0 = m_h[0][i], m1 = m_h[1][i];
        float mm = fmaxf(m0, m1);
        float den = d_h[0][i] * fast_exp(m0 - mm) + d_h[1][i] * fast_exp(m1 - mm);
        mx2[i] = mm; rd2[i] = 1.0f / den;
    }
    __syncthreads();
    // store stats into this block's own attn region (overwritten later)
    float* aout = attn_out + m * 16384;
    if (tid < 128) {
        aout[tid]       = Lv[tid];
        aout[128 + tid] = Rv[tid];
        aout[256 + tid] = mx2[tid];
        aout[384 + tid] = rd2[tid];
    }
    // out2 = attn2 @ Wh2 only for the last timestep of each batch
    if (m % 96 == 95) {
        int b = m / 96;
        int i = tid >> 1, g0 = (tid & 1) * 8;
        float accv[8] = {0.f, 0.f, 0.f, 0.f, 0.f, 0.f, 0.f, 0.f};
        for (int j = 0; j < 128; ++j) {
            float p = 0.f;
            if (adjb[i * 132 + j]) {
                float e = Lv[i] + Rv[j];
                e = e > 0.f ? e : 0.2f * e;
                p = fast_exp(e - mx2[i]) * rd2[i];
            }
#pragma unroll
            for (int g = 0; g < 8; ++g) accv[g] += p * wh2[j * 17 + g0 + g];
        }
#pragma unroll
        for (int g = 0; g < 8; ++g) xg[b * 2048 + i * 16 + g0 + g] = accv[g];
    }
}

// ---------------------------------------------------------------------------
// GAT write: streaming masked softmax. Stages its block's stats to LDS,
// then overwrites the full 16384-float attn tile with float4 ops.
// ---------------------------------------------------------------------------
__global__ __launch_bounds__(256) void gat_write_kernel(
    const float* __restrict__ adj, float* __restrict__ attn_out)
{
    int m = blockIdx.x;
    int tid = threadIdx.x;
    float* aout = attn_out + m * 16384;
    __shared__ float st[512];   // [Lv|Rv|mx2|rd2]
    st[tid] = aout[tid];
    st[256 + tid] = aout[256 + tid];
    __syncthreads();
#pragma unroll 4
    for (int k = 0; k < 16; ++k) {
        int e0 = k * 1024 + tid * 4;
        int i = e0 >> 7, j0 = e0 & 127;
        float Li = st[i], mi = st[256 + i], ri = st[384 + i];
        float4v a = *(const float4v*)(adj + e0);
        float4v p;
#pragma unroll
        for (int u = 0; u < 4; ++u) {
            float pv = 0.f;
            if (a[u] > 0.f) {
                float e = Li + st[128 + j0 + u];
                e = e > 0.f ? e : 0.2f * e;
                pv = fast_exp(e - mi) * ri;
            }
            p[u] = pv;
        }
        *(float4v*)(aout + e0) = p;
    }
}

// ---------------------------------------------------------------------------
// Heads (unchanged)
// ---------------------------------------------------------------------------
__global__ __launch_bounds__(256) void head_partial_kernel(
    const float* __restrict__ xl, const float* __restrict__ xg,
    const float* __restrict__ W1, float* __restrict__ hp)
{
    int k = blockIdx.x >> 4, chunk = blockIdx.x & 15;
    int d = threadIdx.x & 63, bg = threadIdx.x >> 6;
    float acc[4] = {0.f, 0.f, 0.f, 0.f};
    int c0 = chunk * 136;
    for (int cc = c0; cc < c0 + 136; ++cc) {
        float wv = W1[(k * 2176 + cc) * 64 + d];
#pragma unroll
        for (int u = 0; u < 4; ++u) {
            int b = bg * 4 + u;
            float cv = (cc < 128) ? xl[b * 128 + cc] : xg[b * 2048 + cc - 128];
            acc[u] += wv * cv;
        }
    }
#pragma unroll
    for (int u = 0; u < 4; ++u)
        hp[(((k * 16 + chunk) * 16) + bg * 4 + u) * 64 + d] = acc[u];
}

__global__ __launch_bounds__(256) void head_final_kernel(
    const float* __restrict__ hp, const float* __restrict__ b1,
    const float* __restrict__ W2, const float* __restrict__ b2,
    const float* __restrict__ W3d, const float* __restrict__ b3d,
    const float* __restrict__ W3r, const float* __restrict__ b3r,
    const float* __restrict__ W3v, const float* __restrict__ b3v,
    float* __restrict__ out)
{
    __shared__ float h1s[3 * 16 * 64];
    __shared__ float h2s[3 * 16 * 32];
    int tid = threadIdx.x;
    for (int o = tid; o < 3072; o += 256) {
        int k = o >> 10, rem = o & 1023, b = rem >> 6, d = rem & 63;
        float s = b1[k * 64 + d];
        for (int ch = 0; ch < 16; ++ch)
            s += hp[(((k * 16 + ch) * 16) + b) * 64 + d];
        h1s[o] = fmaxf(s, 0.f);
    }
    __syncthreads();
    for (int o = tid; o < 1536; o += 256) {
        int k = o >> 9, rem = o & 511, b = rem >> 5, e = rem & 31;
        float s = b2[k * 32 + e];
        for (int dd = 0; dd < 64; ++dd)
            s += h1s[(k * 16 + b) * 64 + dd] * W2[(k * 64 + dd) * 32 + e];
        h2s[o] = fmaxf(s, 0.f);
    }
    __syncthreads();
    if (tid < 64) {
        if (tid < 16) {
            int b = tid; float s = b3d[0];
            for (int e = 0; e < 32; ++e) s += h2s[b * 32 + e] * W3d[e];
            out[b] = s;
        } else if (tid < 32) {
            int b = tid - 16; float s = b3r[0];
            for (int e = 0; e < 32; ++e) s += h2s[(16 + b) * 32 + e] * W3r[e];
            out[16 + b] = s;
        } else {
            int b = (tid - 32) >> 1, j = tid & 1; float s = b3v[j];
            for (int e = 0; e < 32; ++e) s += h2s[(32 + b) * 32 + e] * W3v[e * 2 + j];
            out[32 + b * 2 + j] = s;
        }
    }
}

// ---------------------------------------------------------------------------
extern "C" void kernel_launch(void* const* d_in, const int* in_sizes, int n_in,
                              void* d_out, int out_size, void* d_ws, size_t ws_size,
                              hipStream_t stream)
{
    const float* x     = (const float*)d_in[0];
    const float* adj   = (const float*)d_in[1];
    const float* W_emb = (const float*)d_in[2];
    const float* b_emb = (const float*)d_in[3];
    const float* W1    = (const float*)d_in[4];
    const float* a1    = (const float*)d_in[5];
    const float* W2    = (const float*)d_in[6];
    const float* a2    = (const float*)d_in[7];
    const float* Wih   = (const float*)d_in[8];
    const float* Whh   = (const float*)d_in[9];
    const float* bih   = (const float*)d_in[10];
    const float* bhh   = (const float*)d_in[11];
    const float* hW1   = (const float*)d_in[12];
    const float* hb1   = (const float*)d_in[13];
    const float* hW2   = (const float*)d_in[14];
    const float* hb2   = (const float*)d_in[15];
    const float* W3d   = (const float*)d_in[16];
    const float* b3d   = (const float*)d_in[17];
    const float* W3r   = (const float*)d_in[18];
    const float* b3r   = (const float*)d_in[19];
    const float* W3v   = (const float*)d_in[20];
    const float* b3v   = (const float*)d_in[21];

    float* out = (float*)d_out;
    // LSTM Pre scratch inside the attn2 region (gat overwrites it afterwards)
    float* SCR = out + 64;

    float* wsf = (float*)d_ws;
    float* XG  = wsf;                   // 16*2048
    float* XL  = wsf + 32768;           // 16*128
    float* HP  = wsf + 34816;           // 3*16*16*64

    lstm_batch_kernel<<<16, 256, 0, stream>>>(x, Wih, Whh, bih, bhh, SCR, XL);
    gat_prep_kernel<<<1536, 256, 0, stream>>>(x, adj, W_emb, b_emb, W1, a1, W2, a2, out + 64, XG);
    gat_write_kernel<<<1536, 256, 0, stream>>>(adj, out + 64);
    head_partial_kernel<<<48, 256, 0, stream>>>(XL, XG, hW1, HP);
    head_final_kernel<<<1, 256, 0, stream>>>(HP, hb1, hW2, hb2, W3d, b3d, W3r, b3r, W3v, b3v, out);
}

// Round 6
// 560.057 us; speedup vs baseline: 1.7425x; 1.7425x over previous
//
#include <hip/hip_runtime.h>
#include <hip/hip_bf16.h>

// ---------------------------------------------------------------------------
// HybridGATLSTM on MI355X — round 6.
//   lstm_batch : 16 blocks x 512 threads, one block per batch element.
//                proj = M=96 MFMA GEMM (split-fp16), as round 4.
//                rec  = fp32 VALU GEMV; thread = (hu, K-chunk c of 32):
//                       owns all 4 gate rows of hu over 32 K (128 VGPR
//                       weights, no spill - round 5's 256-VGPR array spilled),
//                       h in 4 bank-shifted LDS copies (conflict-free),
//                       cross-chunk shfl_xor butterfly, 1 barrier/step.
//                       LDS instrs/step: 264 -> ~136.
//   gat_prep   : per-graph GAT math -> stats into block's own attn region.
//   gat_write  : streaming masked-softmax writer (float4, 100 MB).
//   head_*     : unchanged.
// LSTM Pre scratch lives in the attn2 region of d_out (gat runs after).
// ---------------------------------------------------------------------------

typedef _Float16 half8 __attribute__((ext_vector_type(8)));
typedef float floatx4 __attribute__((ext_vector_type(4)));
typedef float float4v __attribute__((ext_vector_type(4)));

#define LOG2E 1.44269504088896f

__device__ __forceinline__ float fast_exp(float x) {
    return __builtin_amdgcn_exp2f(x * LOG2E);
}
__device__ __forceinline__ float sigm(float x) {
    x = fminf(fmaxf(x, -30.f), 30.f);
    return __builtin_amdgcn_rcpf(1.f + __builtin_amdgcn_exp2f(-x * LOG2E));
}
__device__ __forceinline__ float tanhp(float x) {
    x = fminf(fmaxf(x, -15.f), 15.f);
    float e = __builtin_amdgcn_exp2f(-2.f * LOG2E * x);
    return (1.f - e) * __builtin_amdgcn_rcpf(1.f + e);
}
__device__ __forceinline__ void split8v(float4v v0, float4v v1, half8& hi, half8& lo) {
#pragma unroll
    for (int j = 0; j < 4; ++j) {
        _Float16 h = (_Float16)v0[j];
        hi[j] = h; lo[j] = (_Float16)(v0[j] - (float)h);
    }
#pragma unroll
    for (int j = 0; j < 4; ++j) {
        _Float16 h = (_Float16)v1[j];
        hi[4 + j] = h; lo[4 + j] = (_Float16)(v1[j] - (float)h);
    }
}

// ---------------------------------------------------------------------------
// One block per batch element. Layers sequential; no cross-block traffic.
// ---------------------------------------------------------------------------
__global__ __launch_bounds__(512, 2) void lstm_batch_kernel(
    const float* __restrict__ x,     // [16][96][128]
    const float* __restrict__ Wih,   // [3][512][128]
    const float* __restrict__ Whh,   // [3][512][128]
    const float* __restrict__ bih,   // [3][512]
    const float* __restrict__ bhh,   // [3][512]
    float* __restrict__ scratch,     // per block: 3 * 96*512 floats (Pre)
    float* __restrict__ xl_out)      // [16][128]
{
    int b = blockIdx.x;
    float* PreBase = scratch + b * (3 * 96 * 512);

    int tid = threadIdx.x;
    int w = tid >> 6, lane = tid & 63, quad = lane >> 4, sub = lane & 15;

    // rec decomposition: hu = 16w + sub, K-chunk c = quad (32 K each)
    int hu = 16 * w + sub;
    int c4 = quad;

    __shared__ float hbuf[2][544];     // 2 buffers x 4 bank-shifted copies(136)
    __shared__ float Hseq[96 * 132];   // layer output sequence (padded rows)

    for (int layer = 0; layer < 3; ++layer) {
        const float* WihL = Wih + layer * 65536;
        const float* WhhL = Whh + layer * 65536;
        float* Pre = PreBase + layer * (96 * 512);

        // ======== proj GEMM (MFMA, split-fp16): Pre[t][r] = A[t].Wih[r]+bias
        {
            half8 bhi[4][4], blo[4][4];
            float bias[4];
#pragma unroll
            for (int tt = 0; tt < 4; ++tt) {
                int r = tt * 128 + 16 * w + sub;
                bias[tt] = bih[layer * 512 + r] + bhh[layer * 512 + r];
#pragma unroll
                for (int kc = 0; kc < 4; ++kc) {
                    const float4v* p = (const float4v*)(WihL + r * 128 + kc * 32 + quad * 8);
                    split8v(p[0], p[1], bhi[tt][kc], blo[tt][kc]);
                }
            }
            for (int mt = 0; mt < 6; ++mt) {
                half8 ahi[4], alo[4];
                if (layer == 0) {
                    const float* arow = x + b * 12288 + (mt * 16 + sub) * 128;
#pragma unroll
                    for (int kc = 0; kc < 4; ++kc) {
                        const float4v* p = (const float4v*)(arow + kc * 32 + quad * 8);
                        split8v(p[0], p[1], ahi[kc], alo[kc]);
                    }
                } else {
                    const float* arow = Hseq + (mt * 16 + sub) * 132;
#pragma unroll
                    for (int kc = 0; kc < 4; ++kc) {
                        const float4v* p = (const float4v*)(arow + kc * 32 + quad * 8);
                        split8v(p[0], p[1], ahi[kc], alo[kc]);
                    }
                }
                floatx4 acc[4];
#pragma unroll
                for (int tt = 0; tt < 4; ++tt) {
                    floatx4 a = {bias[tt], bias[tt], bias[tt], bias[tt]};
                    acc[tt] = a;
                }
#pragma unroll
                for (int tt = 0; tt < 4; ++tt)
#pragma unroll
                    for (int kc = 0; kc < 4; ++kc) {
                        acc[tt] = __builtin_amdgcn_mfma_f32_16x16x32_f16(ahi[kc], bhi[tt][kc], acc[tt], 0, 0, 0);
                        acc[tt] = __builtin_amdgcn_mfma_f32_16x16x32_f16(ahi[kc], blo[tt][kc], acc[tt], 0, 0, 0);
                        acc[tt] = __builtin_amdgcn_mfma_f32_16x16x32_f16(alo[kc], bhi[tt][kc], acc[tt], 0, 0, 0);
                    }
                // store: timestep m = mt*16 + quad*4 + reg, row = tt*128+16w+sub
#pragma unroll
                for (int tt = 0; tt < 4; ++tt)
#pragma unroll
                    for (int reg = 0; reg < 4; ++reg)
                        Pre[(mt * 16 + quad * 4 + reg) * 512 + tt * 128 + 16 * w + sub] = acc[tt][reg];
            }
        }

        // ======== recurrence weights: 4 gate rows of hu, K in [32c, 32c+32)
        // 4 x 8 x float4 = 128 VGPRs (must not exceed this: spill cliff)
        float4v wgt[4][8];
#pragma unroll
        for (int g = 0; g < 4; ++g) {
            const float4v* p = (const float4v*)(WhhL + (g * 128 + hu) * 128 + c4 * 32);
#pragma unroll
            for (int k = 0; k < 8; ++k) wgt[g][k] = p[k];
        }
        hbuf[0][c4 * 136 + hu] = 0.f;   // zero all 4 copies of buffer 0
        float cvar = 0.f;
        __syncthreads();   // Pre stores drained; hbuf zeroed; Hseq reads done

        for (int t = 0; t < 96; ++t) {
            int rb = t & 1, wb = rb ^ 1;
            // Pre loads issued early (L2-resident), consumed after butterfly
            float pre[4];
#pragma unroll
            for (int g = 0; g < 4; ++g)
                pre[g] = Pre[t * 512 + g * 128 + hu];

            // h chunk from this lane's bank-shifted copy: banks (8c+4k)%32,
            // distinct across c for fixed k -> conflict-free broadcast
            const float4v* hc = (const float4v*)(&hbuf[rb][c4 * 168]);
            float4v p4[4];
#pragma unroll
            for (int g = 0; g < 4; ++g) {
                float4v z = {0.f, 0.f, 0.f, 0.f};
                p4[g] = z;
            }
#pragma unroll
            for (int k = 0; k < 8; ++k) {
                float4v hv = hc[k];
#pragma unroll
                for (int g = 0; g < 4; ++g) p4[g] += wgt[g][k] * hv;
            }
            float p[4];
#pragma unroll
            for (int g = 0; g < 4; ++g) {
                float s = p4[g].x + p4[g].y + p4[g].z + p4[g].w;
                s += __shfl_xor(s, 16, 64);   // combine chunk pairs
                s += __shfl_xor(s, 32, 64);   // combine halves
                p[g] = s + pre[g];
            }
            // all 4 c-lanes compute identical activations (keeps cvar coherent)
            float c = sigm(p[1]) * cvar + sigm(p[0]) * tanhp(p[2]);
            cvar = c;
            float h = sigm(p[3]) * tanhp(c);
            hbuf[wb][c4 * 136 + hu] = h;      // each lane updates its copy
            if (c4 == 0) {
                if (layer < 2) Hseq[t * 132 + hu] = h;
                else if (t == 95) xl_out[b * 128 + hu] = h;
            }
            __syncthreads();   // h visible; all reads of rb complete
        }
        __syncthreads();
    }
}

// ---------------------------------------------------------------------------
// GAT prep: per-graph stats. Writes [Lv|Rv|mx2|rd2] (512 floats) into the
// first 512 floats of this block's OWN attn region (gat_write stages them to
// LDS before overwriting). Also computes xg for s==95 graphs.
// ---------------------------------------------------------------------------
__global__ __launch_bounds__(256) void gat_prep_kernel(
    const float* __restrict__ x, const float* __restrict__ adj,
    const float* __restrict__ W_emb, const float* __restrict__ b_emb,
    const float* __restrict__ W1, const float* __restrict__ a1,
    const float* __restrict__ W2, const float* __restrict__ a2,
    float* __restrict__ attn_out, float* __restrict__ xg)
{
    int m = blockIdx.x;
    int tid = threadIdx.x;
    __shared__ float xv[128];
    __shared__ unsigned char adjb[128 * 132];
    __shared__ float u1[32], v1[32];
    __shared__ float coef[4];
    __shared__ float s1v[128];
    __shared__ float h2s[128 * 33];
    __shared__ float wh2[128 * 17];
    __shared__ float Lv[128], Rv[128], mx2[128], rd2[128];
    __shared__ float m_h[2][128], d_h[2][128], s_h[2][128];

    if (tid < 128) xv[tid] = x[m * 128 + tid];
    for (int idx = tid; idx < 16384; idx += 256) {
        int i = idx >> 7, j = idx & 127;
        adjb[i * 132 + j] = adj[idx] > 0.f ? 1 : 0;
    }
    if (tid < 32) {
        float su = 0.f, sv = 0.f;
        for (int kk = 0; kk < 32; ++kk) {
            su += W_emb[kk] * W1[kk * 32 + tid];
            sv += b_emb[kk] * W1[kk * 32 + tid];
        }
        u1[tid] = su; v1[tid] = sv;
    }
    __syncthreads();
    if (tid < 4) {
        const float* av = a1 + ((tid >= 2) ? 32 : 0);
        const float* uv = (tid & 1) ? v1 : u1;
        float s = 0.f;
        for (int f = 0; f < 32; ++f) s += uv[f] * av[f];
        coef[tid] = s;
    }
    __syncthreads();
    float cL = coef[0], dL = coef[1], cR = coef[2], dR = coef[3];

    // GAT1 softmax stats + weighted scalar sum (FI=1 collapse)
    {
        int i = tid & 127, hf = tid >> 7;
        float Li = xv[i] * cL + dL;
        int j0 = hf * 64;
        float mmax = -3.0e38f;
        for (int j = j0; j < j0 + 64; ++j) {
            if (adjb[i * 132 + j]) {
                float e = Li + xv[j] * cR + dR;
                e = e > 0.f ? e : 0.2f * e;
                mmax = fmaxf(mmax, e);
            }
        }
        float den = 0.f, wsum = 0.f;
        for (int j = j0; j < j0 + 64; ++j) {
            if (adjb[i * 132 + j]) {
                float e = Li + xv[j] * cR + dR;
                e = e > 0.f ? e : 0.2f * e;
                float p = fast_exp(e - mmax);
                den += p; wsum += p * xv[j];
            }
        }
        m_h[hf][i] = mmax; d_h[hf][i] = den; s_h[hf][i] = wsum;
    }
    __syncthreads();
    if (tid < 128) {
        int i = tid;
        float m0 = m_h[0][i], m1 = m_h[1][i];
        float mm = fmaxf(m0, m1);
        float sc0 = fast_exp(m0 - mm), sc1 = fast_exp(m1 - mm);
        float den = d_h[0][i] * sc0 + d_h[1][i] * sc1;
        float wsum = s_h[0][i] * sc0 + s_h[1][i] * sc1;
        s1v[i] = wsum / den;
    }
    __syncthreads();
    // h2 = elu(s1*u1 + v1)
    for (int e = tid; e < 4096; e += 256) {
        int i = e >> 5, f = e & 31;
        float v = s1v[i] * u1[f] + v1[f];
        h2s[i * 33 + f] = v > 0.f ? v : fast_exp(v) - 1.f;
    }
    __syncthreads();
    // Wh2 = h2 @ W2 (128x32 @ 32x16)
    {
        int i = tid >> 1, g0 = (tid & 1) * 8;
        float accv[8] = {0.f, 0.f, 0.f, 0.f, 0.f, 0.f, 0.f, 0.f};
        for (int f = 0; f < 32; ++f) {
            float hv = h2s[i * 33 + f];
#pragma unroll
            for (int g = 0; g < 8; ++g) accv[g] += hv * W2[f * 16 + g0 + g];
        }
#pragma unroll
        for (int g = 0; g < 8; ++g) wh2[i * 17 + g0 + g] = accv[g];
    }
    __syncthreads();
    {
        int i = tid & 127, which = tid >> 7;
        const float* aa = a2 + which * 16;
        float s = 0.f;
        for (int g = 0; g < 16; ++g) s += wh2[i * 17 + g] * aa[g];
        (which ? Rv : Lv)[i] = s;
    }
    __syncthreads();
    // attn2 softmax stats
    {
        int i = tid & 127, hf = tid >> 7;
        float Li = Lv[i];
        int j0 = hf * 64;
        float mmax = -3.0e38f;
        for (int j = j0; j < j0 + 64; ++j) {
            if (adjb[i * 132 + j]) {
                float e = Li + Rv[j];
                e = e > 0.f ? e : 0.2f * e;
                mmax = fmaxf(mmax, e);
            }
        }
        float den = 0.f;
        for (int j = j0; j < j0 + 64; ++j) {
            if (adjb[i * 132 + j]) {
                float e = Li + Rv[j];
                e = e > 0.f ? e : 0.2f * e;
                den += fast_exp(e - mmax);
            }
        }
        m_h[hf][i] = mmax; d_h[hf][i] = den;
    }
    __syncthreads();
    if (tid < 128) {
        int i = tid;
        float m0 = m_h[0][i], m1 = m_h[1][i];
        float mm = fmaxf(m0, m1);
        float den = d_h[0][i] * fast_exp(m0 - mm) + d_h[1][i] * fast_exp(m1 - mm);
        mx2[i] = mm; rd2[i] = 1.0f / den;
    }
    __syncthreads();
    // store stats into this block's own attn region (overwritten later)
    float* aout = attn_out + m * 16384;
    if (tid < 128) {
        aout[tid]       = Lv[tid];
        aout[128 + tid] = Rv[tid];
        aout[256 + tid] = mx2[tid];
        aout[384 + tid] = rd2[tid];
    }
    // out2 = attn2 @ Wh2 only for the last timestep of each batch
    if (m % 96 == 95) {
        int b = m / 96;
        int i = tid >> 1, g0 = (tid & 1) * 8;
        float accv[8] = {0.f, 0.f, 0.f, 0.f, 0.f, 0.f, 0.f, 0.f};
        for (int j = 0; j < 128; ++j) {
            float p = 0.f;
            if (adjb[i * 132 + j]) {
                float e = Lv[i] + Rv[j];
                e = e > 0.f ? e : 0.2f * e;
                p = fast_exp(e - mx2[i]) * rd2[i];
            }
#pragma unroll
            for (int g = 0; g < 8; ++g) accv[g] += p * wh2[j * 17 + g0 + g];
        }
#pragma unroll
        for (int g = 0; g < 8; ++g) xg[b * 2048 + i * 16 + g0 + g] = accv[g];
    }
}

// ---------------------------------------------------------------------------
// GAT write: streaming masked softmax. Stages its block's stats to LDS,
// then overwrites the full 16384-float attn tile with float4 ops.
// ---------------------------------------------------------------------------
__global__ __launch_bounds__(256) void gat_write_kernel(
    const float* __restrict__ adj, float* __restrict__ attn_out)
{
    int m = blockIdx.x;
    int tid = threadIdx.x;
    float* aout = attn_out + m * 16384;
    __shared__ float st[512];   // [Lv|Rv|mx2|rd2]
    st[tid] = aout[tid];
    st[256 + tid] = aout[256 + tid];
    __syncthreads();
#pragma unroll 4
    for (int k = 0; k < 16; ++k) {
        int e0 = k * 1024 + tid * 4;
        int i = e0 >> 7, j0 = e0 & 127;
        float Li = st[i], mi = st[256 + i], ri = st[384 + i];
        float4v a = *(const float4v*)(adj + e0);
        float4v p;
#pragma unroll
        for (int u = 0; u < 4; ++u) {
            float pv = 0.f;
            if (a[u] > 0.f) {
                float e = Li + st[128 + j0 + u];
                e = e > 0.f ? e : 0.2f * e;
                pv = fast_exp(e - mi) * ri;
            }
            p[u] = pv;
        }
        *(float4v*)(aout + e0) = p;
    }
}

// ---------------------------------------------------------------------------
// Heads (unchanged)
// ---------------------------------------------------------------------------
__global__ __launch_bounds__(256) void head_partial_kernel(
    const float* __restrict__ xl, const float* __restrict__ xg,
    const float* __restrict__ W1, float* __restrict__ hp)
{
    int k = blockIdx.x >> 4, chunk = blockIdx.x & 15;
    int d = threadIdx.x & 63, bg = threadIdx.x >> 6;
    float acc[4] = {0.f, 0.f, 0.f, 0.f};
    int c0 = chunk * 136;
    for (int cc = c0; cc < c0 + 136; ++cc) {
        float wv = W1[(k * 2176 + cc) * 64 + d];
#pragma unroll
        for (int u = 0; u < 4; ++u) {
            int b = bg * 4 + u;
            float cv = (cc < 128) ? xl[b * 128 + cc] : xg[b * 2048 + cc - 128];
            acc[u] += wv * cv;
        }
    }
#pragma unroll
    for (int u = 0; u < 4; ++u)
        hp[(((k * 16 + chunk) * 16) + bg * 4 + u) * 64 + d] = acc[u];
}

__global__ __launch_bounds__(256) void head_final_kernel(
    const float* __restrict__ hp, const float* __restrict__ b1,
    const float* __restrict__ W2, const float* __restrict__ b2,
    const float* __restrict__ W3d, const float* __restrict__ b3d,
    const float* __restrict__ W3r, const float* __restrict__ b3r,
    const float* __restrict__ W3v, const float* __restrict__ b3v,
    float* __restrict__ out)
{
    __shared__ float h1s[3 * 16 * 64];
    __shared__ float h2s[3 * 16 * 32];
    int tid = threadIdx.x;
    for (int o = tid; o < 3072; o += 256) {
        int k = o >> 10, rem = o & 1023, b = rem >> 6, d = rem & 63;
        float s = b1[k * 64 + d];
        for (int ch = 0; ch < 16; ++ch)
            s += hp[(((k * 16 + ch) * 16) + b) * 64 + d];
        h1s[o] = fmaxf(s, 0.f);
    }
    __syncthreads();
    for (int o = tid; o < 1536; o += 256) {
        int k = o >> 9, rem = o & 511, b = rem >> 5, e = rem & 31;
        float s = b2[k * 32 + e];
        for (int dd = 0; dd < 64; ++dd)
            s += h1s[(k * 16 + b) * 64 + dd] * W2[(k * 64 + dd) * 32 + e];
        h2s[o] = fmaxf(s, 0.f);
    }
    __syncthreads();
    if (tid < 64) {
        if (tid < 16) {
            int b = tid; float s = b3d[0];
            for (int e = 0; e < 32; ++e) s += h2s[b * 32 + e] * W3d[e];
            out[b] = s;
        } else if (tid < 32) {
            int b = tid - 16; float s = b3r[0];
            for (int e = 0; e < 32; ++e) s += h2s[(16 + b) * 32 + e] * W3r[e];
            out[16 + b] = s;
        } else {
            int b = (tid - 32) >> 1, j = tid & 1; float s = b3v[j];
            for (int e = 0; e < 32; ++e) s += h2s[(32 + b) * 32 + e] * W3v[e * 2 + j];
            out[32 + b * 2 + j] = s;
        }
    }
}

// ---------------------------------------------------------------------------
extern "C" void kernel_launch(void* const* d_in, const int* in_sizes, int n_in,
                              void* d_out, int out_size, void* d_ws, size_t ws_size,
                              hipStream_t stream)
{
    const float* x     = (const float*)d_in[0];
    const float* adj   = (const float*)d_in[1];
    const float* W_emb = (const float*)d_in[2];
    const float* b_emb = (const float*)d_in[3];
    const float* W1    = (const float*)d_in[4];
    const float* a1    = (const float*)d_in[5];
    const float* W2    = (const float*)d_in[6];
    const float* a2    = (const float*)d_in[7];
    const float* Wih   = (const float*)d_in[8];
    const float* Whh   = (const float*)d_in[9];
    const float* bih   = (const float*)d_in[10];
    const float* bhh   = (const float*)d_in[11];
    const float* hW1   = (const float*)d_in[12];
    const float* hb1   = (const float*)d_in[13];
    const float* hW2   = (const float*)d_in[14];
    const float* hb2   = (const float*)d_in[15];
    const float* W3d   = (const float*)d_in[16];
    const float* b3d   = (const float*)d_in[17];
    const float* W3r   = (const float*)d_in[18];
    const float* b3r   = (const float*)d_in[19];
    const float* W3v   = (const float*)d_in[20];
    const float* b3v   = (const float*)d_in[21];

    float* out = (float*)d_out;
    // LSTM Pre scratch inside the attn2 region (gat overwrites it afterwards)
    float* SCR = out + 64;

    float* wsf = (float*)d_ws;
    float* XG  = wsf;                   // 16*2048
    float* XL  = wsf + 32768;           // 16*128
    float* HP  = wsf + 34816;           // 3*16*16*64

    lstm_batch_kernel<<<16, 512, 0, stream>>>(x, Wih, Whh, bih, bhh, SCR, XL);
    gat_prep_kernel<<<1536, 256, 0, stream>>>(x, adj, W_emb, b_emb, W1, a1, W2, a2, out + 64, XG);
    gat_write_kernel<<<1536, 256, 0, stream>>>(adj, out + 64);
    head_partial_kernel<<<48, 256, 0, stream>>>(XL, XG, hW1, HP);
    head_final_kernel<<<1, 256, 0, stream>>>(HP, hb1, hW2, hb2, W3d, b3d, W3r, b3r, W3v, b3v, out);
}